// Round 1
// baseline (550.108 us; speedup 1.0000x reference)
//
#include <hip/hip_runtime.h>
#include <stdint.h>
#include <stddef.h>

#define BATCH 32768
#define HDIM  1024
#define NFAM  10

typedef short bf16x8 __attribute__((ext_vector_type(8)));
typedef float f32x4  __attribute__((ext_vector_type(4)));

// fp32 -> bf16 round-to-nearest-even (bit-level, no dependence on hip_bf16 internals)
__device__ __forceinline__ unsigned short f2bf(float x) {
  unsigned int u = __builtin_bit_cast(unsigned int, x);
  u += 0x7fffu + ((u >> 16) & 1u);
  return (unsigned short)(u >> 16);
}

// async global->LDS, 16B per lane. LDS dest must be wave-uniform base + lane*16.
__device__ __forceinline__ void async_cp16(unsigned short* lds_dst, const unsigned short* g_src) {
  __builtin_amdgcn_global_load_lds(
      (const __attribute__((address_space(1))) unsigned int*)g_src,
      (__attribute__((address_space(3))) unsigned int*)lds_dst,
      16, 0, 0);
}

// ---------------------------------------------------------------------------
// Transpose + cast: in f32 [R][C] row-major -> out bf16 [C][R] (out[c][r]=in[r][c])
// ---------------------------------------------------------------------------
__global__ __launch_bounds__(256) void transpose_cast(
    const float* __restrict__ in, unsigned short* __restrict__ out, int R, int C) {
  __shared__ float tile[64][65];  // +1 pad: conflict-free transposed reads
  const int t = threadIdx.x;
  const int c = t & 63;
  const int r0 = t >> 6;
  const int rbase = blockIdx.y * 64, cbase = blockIdx.x * 64;
#pragma unroll
  for (int i = 0; i < 16; ++i) {
    int r = r0 + i * 4;
    tile[r][c] = in[(size_t)(rbase + r) * C + cbase + c];
  }
  __syncthreads();
#pragma unroll
  for (int i = 0; i < 16; ++i) {
    int r = r0 + i * 4;
    out[(size_t)(cbase + r) * R + rbase + c] = f2bf(tile[c][r]);
  }
}

// ---------------------------------------------------------------------------
// Prototype prep: bf16 copy + squared norms. One block per family.
// ---------------------------------------------------------------------------
__global__ __launch_bounds__(256) void proto_prep(
    const float* __restrict__ protos, unsigned short* __restrict__ protosB,
    float* __restrict__ p2) {
  __shared__ float red[4];
  const int j = blockIdx.x, t = threadIdx.x;
  float4 v = ((const float4*)(protos + (size_t)j * HDIM))[t];
  uint2 pk;
  pk.x = (unsigned)f2bf(v.x) | ((unsigned)f2bf(v.y) << 16);
  pk.y = (unsigned)f2bf(v.z) | ((unsigned)f2bf(v.w) << 16);
  *(uint2*)(protosB + (size_t)j * HDIM + t * 4) = pk;
  float s = v.x * v.x + v.y * v.y + v.z * v.z + v.w * v.w;
#pragma unroll
  for (int o = 32; o > 0; o >>= 1) s += __shfl_down(s, o);
  if ((t & 63) == 0) red[t >> 6] = s;
  __syncthreads();
  if (t == 0) p2[j] = red[0] + red[1] + red[2] + red[3];
}

// ---------------------------------------------------------------------------
// Nearest prototype + features->bf16 cast. One wave (64 lanes) per row.
// block = 256 threads = 4 rows; grid = BATCH/4.
// ---------------------------------------------------------------------------
__global__ __launch_bounds__(256) void nearest_kernel(
    const float* __restrict__ feats, const float* __restrict__ protos,
    const float* __restrict__ p2, unsigned short* __restrict__ featsB,
    int* __restrict__ idx) {
  const int row  = blockIdx.x * 4 + (threadIdx.x >> 6);
  const int lane = threadIdx.x & 63;
  const float* f = feats + (size_t)row * HDIM;

  float dot[NFAM];
#pragma unroll
  for (int j = 0; j < NFAM; ++j) dot[j] = 0.f;
  float f2 = 0.f;

#pragma unroll
  for (int ch = 0; ch < 4; ++ch) {
    const int k = ch * 256 + lane * 4;
    float4 v = *(const float4*)(f + k);
    f2 += v.x * v.x + v.y * v.y + v.z * v.z + v.w * v.w;
#pragma unroll
    for (int j = 0; j < NFAM; ++j) {
      float4 p = *(const float4*)(protos + (size_t)j * HDIM + k);
      dot[j] += v.x * p.x + v.y * p.y + v.z * p.z + v.w * p.w;
    }
    uint2 pk;
    pk.x = (unsigned)f2bf(v.x) | ((unsigned)f2bf(v.y) << 16);
    pk.y = (unsigned)f2bf(v.z) | ((unsigned)f2bf(v.w) << 16);
    *(uint2*)(featsB + (size_t)row * HDIM + k) = pk;
  }

#pragma unroll
  for (int o = 32; o > 0; o >>= 1) {
    f2 += __shfl_down(f2, o);
#pragma unroll
    for (int j = 0; j < NFAM; ++j) dot[j] += __shfl_down(dot[j], o);
  }
  if (lane == 0) {
    int best = 0;
    float bd = f2 + p2[0] - 2.f * dot[0];
#pragma unroll
    for (int j = 1; j < NFAM; ++j) {
      float d = f2 + p2[j] - 2.f * dot[j];
      if (d < bd) { bd = d; best = j; }  // strict <: first-min tie-break == jnp.argmin
    }
    idx[row] = best;
  }
}

// ---------------------------------------------------------------------------
// bf16 GEMM, m97 ladder structure: 128x128 tile, BK=32, 256 threads (4 waves,
// each wave a 64x64 quadrant as 4x4 grid of 16x16x32 MFMAs), width-16
// global_load_lds staging.
// GATHER: A row k<1024 from A (features), k>=1024 from P[idx[row]] (prototype).
// RELU_BF16: out = bf16(relu(acc+bias)) to outB; else f32 acc+bias to outF.
// N is fixed at 1024 for both GEMMs.
// ---------------------------------------------------------------------------
template <int GATHER, int RELU_BF16>
__global__ __launch_bounds__(256) void gemm_kernel(
    const unsigned short* __restrict__ A,   // [M][1024] bf16
    const unsigned short* __restrict__ P,   // [NFAM][1024] bf16 (GATHER)
    const int* __restrict__ idx,            // [M] (GATHER)
    const unsigned short* __restrict__ Bt,  // [1024][K] bf16, n-major
    const float* __restrict__ bias,         // [1024]
    unsigned short* __restrict__ outB,      // [M][1024] bf16
    float* __restrict__ outF,               // [M][1024] f32
    int K) {
  __shared__ unsigned short ldsA[128 * 32];  // [row][k] row-major, 64B rows
  __shared__ unsigned short ldsB[128 * 32];  // [n][k]  row-major
  __shared__ int idxLds[128];

  const int t    = threadIdx.x;
  const int lane = t & 63;
  const int wid  = t >> 6;
  const int quad = lane >> 4;
  const int r16  = lane & 15;
  const int rowBase = blockIdx.x * 128;
  const int colBase = blockIdx.y * 128;
  const int wm = (wid >> 1) * 64;
  const int wn = (wid & 1) * 64;

  if (GATHER) {
    if (t < 128) idxLds[t] = idx[rowBase + t];
  }
  __syncthreads();

  f32x4 acc[4][4];
#pragma unroll
  for (int i = 0; i < 4; ++i)
#pragma unroll
    for (int j = 0; j < 4; ++j) acc[i][j] = (f32x4){0.f, 0.f, 0.f, 0.f};

  // staging chunk mapping: chunk c in [0,512): LDS row = c>>2, 16B piece = c&3
  const int c0 = t, c1 = t + 256;
  const int rA0 = c0 >> 2, pA0 = c0 & 3;
  const int rA1 = c1 >> 2, pA1 = c1 & 3;

  for (int kb = 0; kb < K; kb += 32) {
    const unsigned short* s0;
    const unsigned short* s1;
    if (!GATHER || kb < 1024) {
      s0 = A + (size_t)(rowBase + rA0) * 1024 + kb + pA0 * 8;
      s1 = A + (size_t)(rowBase + rA1) * 1024 + kb + pA1 * 8;
    } else {
      s0 = P + (size_t)idxLds[rA0] * 1024 + (kb - 1024) + pA0 * 8;
      s1 = P + (size_t)idxLds[rA1] * 1024 + (kb - 1024) + pA1 * 8;
    }
    async_cp16(ldsA + c0 * 8, s0);
    async_cp16(ldsA + c1 * 8, s1);
    async_cp16(ldsB + c0 * 8, Bt + (size_t)(colBase + rA0) * K + kb + pA0 * 8);
    async_cp16(ldsB + c1 * 8, Bt + (size_t)(colBase + rA1) * K + kb + pA1 * 8);
    __syncthreads();  // drains vmcnt before barrier

    bf16x8 af[4], bfr[4];
#pragma unroll
    for (int mi = 0; mi < 4; ++mi)
      af[mi] = *(const bf16x8*)(ldsA + (wm + mi * 16 + r16) * 32 + quad * 8);
#pragma unroll
    for (int ni = 0; ni < 4; ++ni)
      bfr[ni] = *(const bf16x8*)(ldsB + (wn + ni * 16 + r16) * 32 + quad * 8);
#pragma unroll
    for (int mi = 0; mi < 4; ++mi)
#pragma unroll
      for (int ni = 0; ni < 4; ++ni)
        acc[mi][ni] = __builtin_amdgcn_mfma_f32_16x16x32_bf16(af[mi], bfr[ni], acc[mi][ni], 0, 0, 0);
    __syncthreads();
  }

  // epilogue: C/D layout col=lane&15, row=quad*4+reg  [m89/m91]
#pragma unroll
  for (int mi = 0; mi < 4; ++mi) {
#pragma unroll
    for (int ni = 0; ni < 4; ++ni) {
      const int grow0 = rowBase + wm + mi * 16 + quad * 4;
      const int gcol  = colBase + wn + ni * 16 + r16;
      const float bv = bias[gcol];
#pragma unroll
      for (int r = 0; r < 4; ++r) {
        float v = acc[mi][ni][r] + bv;
        if (RELU_BF16) {
          v = fmaxf(v, 0.0f);
          outB[(size_t)(grow0 + r) * 1024 + gcol] = f2bf(v);
        } else {
          outF[(size_t)(grow0 + r) * 1024 + gcol] = v;
        }
      }
    }
  }
}

// ---------------------------------------------------------------------------
// Workspace layout (bytes):
//   featsB  : BATCH*HDIM bf16   =  67,108,864
//   hiddenB : BATCH*HDIM bf16   =  67,108,864
//   W1t     : [1024][2048] bf16 =   4,194,304
//   W2t     : [1024][1024] bf16 =   2,097,152
//   protosB : [10][1024] bf16   =      20,480
//   p2      : 10 f32            =          40
//   idx     : BATCH i32         =     131,072
//   total ≈ 140.7 MB
// ---------------------------------------------------------------------------
extern "C" void kernel_launch(void* const* d_in, const int* in_sizes, int n_in,
                              void* d_out, int out_size, void* d_ws, size_t ws_size,
                              hipStream_t stream) {
  const float* feats  = (const float*)d_in[0];
  const float* protos = (const float*)d_in[1];
  const float* W1     = (const float*)d_in[2];
  const float* b1     = (const float*)d_in[3];
  const float* W2     = (const float*)d_in[4];
  const float* b2     = (const float*)d_in[5];
  float* out = (float*)d_out;

  unsigned short* featsB  = (unsigned short*)d_ws;
  unsigned short* hiddenB = featsB + (size_t)BATCH * HDIM;
  unsigned short* W1t     = hiddenB + (size_t)BATCH * HDIM;
  unsigned short* W2t     = W1t + (size_t)2 * HDIM * HDIM;
  unsigned short* protosB = W2t + (size_t)HDIM * HDIM;
  float* p2 = (float*)(protosB + NFAM * HDIM);
  int* idx  = (int*)(p2 + NFAM + 2);

  // W1 [2048][1024] -> W1t [1024][2048]; W2 [1024][1024] -> W2t [1024][1024]
  transpose_cast<<<dim3(HDIM / 64, 2 * HDIM / 64), 256, 0, stream>>>(W1, W1t, 2 * HDIM, HDIM);
  transpose_cast<<<dim3(HDIM / 64, HDIM / 64), 256, 0, stream>>>(W2, W2t, HDIM, HDIM);
  proto_prep<<<NFAM, 256, 0, stream>>>(protos, protosB, p2);
  nearest_kernel<<<BATCH / 4, 256, 0, stream>>>(feats, protos, p2, featsB, idx);
  // GEMM1: hidden = relu([feats | proto[idx]] @ W1 + b1)   K=2048
  gemm_kernel<1, 1><<<dim3(BATCH / 128, HDIM / 128), 256, 0, stream>>>(
      featsB, protosB, idx, W1t, b1, hiddenB, nullptr, 2 * HDIM);
  // GEMM2: out = hidden @ W2 + b2                          K=1024
  gemm_kernel<0, 0><<<dim3(BATCH / 128, HDIM / 128), 256, 0, stream>>>(
      hiddenB, nullptr, nullptr, W2t, b2, nullptr, out, HDIM);
}